// Round 12
// baseline (378.515 us; speedup 1.0000x reference)
//
#include <hip/hip_runtime.h>

#define DIM   256
#define KCB   8192
#define NTOK  32768
#define NSPLIT 2
#define CPS   4096      // codes per split

using half8 = __attribute__((ext_vector_type(8))) _Float16;
using half4 = __attribute__((ext_vector_type(4))) _Float16;
using f32x4 = __attribute__((ext_vector_type(4))) float;

#define GLOBAL_AS(p) ((const __attribute__((address_space(1))) void*)(p))
#define LDS_AS(p)    ((__attribute__((address_space(3))) void*)(p))

__device__ __forceinline__ void ins2(float v, int i, float& b1v, int& b1i,
                                     float& b2v, int& b2i) {
    bool bet1 = (v < b1v) || (v == b1v && i < b1i);
    bool bet2 = (v < b2v) || (v == b2v && i < b2i);
    if (bet1) { b2v = b1v; b2i = b1i; b1v = v; b1i = i; }
    else if (bet2) { b2v = v; b2i = i; }
}

// ---------------- split fp32 rows into fp16 hi (+ optional lo, + optional norms) ----------------
__global__ __launch_bounds__(256) void k_split(const float* __restrict__ src,
                                               _Float16* __restrict__ hi,
                                               _Float16* __restrict__ lo,
                                               float* __restrict__ norm, int nrows) {
    int row = (int)((blockIdx.x * blockDim.x + threadIdx.x) >> 6);
    int lane = threadIdx.x & 63;
    if (row >= nrows) return;
    float4 v = *(const float4*)&src[(size_t)row * DIM + lane * 4];
    float vv[4] = {v.x, v.y, v.z, v.w};
    half4 hh, hl;
    #pragma unroll
    for (int j = 0; j < 4; ++j) {
        _Float16 h = (_Float16)vv[j];
        hh[j] = h;
        hl[j] = (_Float16)(vv[j] - (float)h);
    }
    *(half4*)&hi[(size_t)row * DIM + lane * 4] = hh;
    if (lo) *(half4*)&lo[(size_t)row * DIM + lane * 4] = hl;
    if (norm) {
        float s = v.x*v.x + v.y*v.y + v.z*v.z + v.w*v.w;
        #pragma unroll
        for (int m = 32; m; m >>= 1) s += __shfl_xor(s, m);
        if (lane == 0) norm[row] = s;
    }
}

// ---------------- z = x @ W^T + b via fp16x3 MFMA, stored as (zh, zl) ----------------
__global__ __launch_bounds__(256) void k_linear(const float* __restrict__ x,
                                                const _Float16* __restrict__ wh,
                                                const _Float16* __restrict__ wl,
                                                const float* __restrict__ bias,
                                                _Float16* __restrict__ zh,
                                                _Float16* __restrict__ zl) {
    const int tid = threadIdx.x;
    const int w = tid >> 6, lane = tid & 63;
    const int col = lane & 15, kg = lane >> 4;
    const int m0 = blockIdx.x * 64;
    const int e0 = w * 64;

    f32x4 acc[4][4];
    #pragma unroll
    for (int mi = 0; mi < 4; ++mi)
        #pragma unroll
        for (int nj = 0; nj < 4; ++nj) acc[mi][nj] = (f32x4){0.f, 0.f, 0.f, 0.f};

    for (int kc = 0; kc < 8; ++kc) {
        half8 ah[4], al[4], bh[4], bl[4];
        #pragma unroll
        for (int mi = 0; mi < 4; ++mi) {
            const float* p = &x[(size_t)(m0 + mi * 16 + col) * DIM + kc * 32 + kg * 8];
            float4 v0 = *(const float4*)p;
            float4 v1 = *(const float4*)(p + 4);
            float vv[8] = {v0.x, v0.y, v0.z, v0.w, v1.x, v1.y, v1.z, v1.w};
            #pragma unroll
            for (int j = 0; j < 8; ++j) {
                _Float16 h = (_Float16)vv[j];
                ah[mi][j] = h;
                al[mi][j] = (_Float16)(vv[j] - (float)h);
            }
        }
        #pragma unroll
        for (int nj = 0; nj < 4; ++nj) {
            size_t off = (size_t)(e0 + nj * 16 + col) * DIM + kc * 32 + kg * 8;
            bh[nj] = *(const half8*)&wh[off];
            bl[nj] = *(const half8*)&wl[off];
        }
        #pragma unroll
        for (int mi = 0; mi < 4; ++mi)
            #pragma unroll
            for (int nj = 0; nj < 4; ++nj) {
                acc[mi][nj] = __builtin_amdgcn_mfma_f32_16x16x32_f16(ah[mi], bh[nj], acc[mi][nj], 0, 0, 0);
                acc[mi][nj] = __builtin_amdgcn_mfma_f32_16x16x32_f16(ah[mi], bl[nj], acc[mi][nj], 0, 0, 0);
                acc[mi][nj] = __builtin_amdgcn_mfma_f32_16x16x32_f16(al[mi], bh[nj], acc[mi][nj], 0, 0, 0);
            }
    }
    #pragma unroll
    for (int nj = 0; nj < 4; ++nj) {
        int e = e0 + nj * 16 + col;
        float bv = bias[e];
        #pragma unroll
        for (int mi = 0; mi < 4; ++mi)
            #pragma unroll
            for (int r = 0; r < 4; ++r) {
                int m = m0 + mi * 16 + kg * 4 + r;
                float zv = acc[mi][nj][r] + bv;
                _Float16 h = (_Float16)zv;
                zh[(size_t)m * DIM + e] = h;
                zl[(size_t)m * DIM + e] = (_Float16)(zv - (float)h);
            }
    }
}

// ---------------- fp16 MFMA distance argmin; 128-tok tiles + double-buffered BK=32 pipeline ----------------
// R11 (128-tok, single-buffered): 247 us, staged BW 4.3 TB/s < the ~6.5 TB/s delivery ceiling
// observed at R6/R9 -> no longer delivery-bound; the stall is the per-step stage-drain serialization.
// This round: chunk = 128 codes x 32 dims (8 KB), DOUBLE-buffered (16 KB) + A 64 KB = 80 KB
// -> still 2 blocks/CU. 256 steps; step c:
//   barrier1 (readers of buf[(c+1)&1] done) ; STAGE(c+1) ; vmcnt(2) (own chunk-c landed,
//   c+1 in flight) ; barrier2 (all waves' chunk-c landed) ; 16 MFMA.
// Stage latency hides under a full step. vmcnt retires in order, so the 4 cnorm loads at tile
// boundaries only strengthen the wait (R7-proven correctness pattern).
// B LDS layout = R5-proven paired-row 3-bit XOR: slot8(r,kg) = (r>>1)*8 + (((r&1)*4+kg)^((r>>1)&7)).
__global__ __launch_bounds__(256, 1) void k_argmin(const _Float16* __restrict__ zh,
                                                   const _Float16* __restrict__ ch,
                                                   const float* __restrict__ cnorm,
                                                   float4* __restrict__ cand) {
    extern __shared__ __align__(16) char smem[];
    const int tid = threadIdx.x;
    const int w = tid >> 6, lane = tid & 63;
    const int wm = w >> 1, wn = w & 1;
    const int col = lane & 15, kg = lane >> 4;
    const int split = blockIdx.x & 1;
    const int m0 = (blockIdx.x >> 1) * 128;

    // ---- stage A once: 128 rows x 512 B, LDS[row][gp] = Z[row][gp ^ (row&15)]  (16 loads/thread)
    #pragma unroll
    for (int j = 0; j < 16; ++j) {
        int s = j * 256 + w * 64 + lane;          // 16B slot 0..4095
        int row = s >> 5;                         // token row 0..127
        int gp = s & 31;
        int g = gp ^ (row & 15);
        const _Float16* src = zh + (size_t)(m0 + row) * DIM + g * 8;
        __builtin_amdgcn_global_load_lds(GLOBAL_AS(src),
            LDS_AS(smem + j * 4096 + w * 1024), 16, 0, 0);
    }

    // ---- B staging: per-thread global element offsets (loop-invariant part).
    // Thread slot s = j*256 + tid (j=0,1) of the 512-slot 8 KB chunk; decode R5 layout:
    size_t eb[2];
    #pragma unroll
    for (int j = 0; j < 2; ++j) {
        int s  = j * 256 + w * 64 + lane;   // 16B slot 0..511
        int rr = s >> 3, q = s & 7;
        int g2 = q ^ (rr & 7);
        int r  = rr * 2 + (g2 >> 2);        // code row 0..127
        int kg4 = g2 & 3;                   // 16B group within 64B k-slice
        eb[j] = (size_t)(split * CPS + r) * DIM + kg4 * 8;
    }
    // ---- per-thread B-read byte offsets (loop-invariant)
    int bslot[4];
    #pragma unroll
    for (int nj = 0; nj < 4; ++nj) {
        int r = wn * 64 + nj * 16 + col;    // code row 0..127 in chunk
        bslot[nj] = (((r >> 1) << 3) + ((((r & 1) << 2) + kg) ^ ((r >> 1) & 7))) << 4;
    }

    auto STAGE = [&](int cc, int buf) {
        size_t off = (size_t)(cc >> 3) * 128 * DIM + (cc & 7) * 32;   // uniform across lanes
        char* dst = smem + 65536 + buf * 8192 + w * 1024;
        #pragma unroll
        for (int j = 0; j < 2; ++j)
            __builtin_amdgcn_global_load_lds(GLOBAL_AS(ch + eb[j] + off),
                                             LDS_AS(dst + j * 4096), 16, 0, 0);
    };

    STAGE(0, 0);   // chunk 0; A (16) + 2 = 18 outstanding

    float val[16];
    unsigned pidx[8];
    #pragma unroll
    for (int s = 0; s < 16; ++s) val[s] = 3.4e38f;
    #pragma unroll
    for (int s = 0; s < 8; ++s) pidx[s] = 0xFFFFFFFFu;

    f32x4 acc[4][4];
    #pragma unroll
    for (int mi = 0; mi < 4; ++mi)
        #pragma unroll
        for (int nj = 0; nj < 4; ++nj) acc[mi][nj] = (f32x4){0.f, 0.f, 0.f, 0.f};

    const _Float16* zbuf = (const _Float16*)smem;

    for (int nt = 0; nt < 32; ++nt) {
        #pragma unroll
        for (int ks = 0; ks < 8; ++ks) {
            const int c = nt * 8 + ks;
            __builtin_amdgcn_s_barrier();            // readers of buf[(c+1)&1] (chunk c-1) done
            if (c < 255) {
                STAGE(c + 1, (ks + 1) & 1);
                asm volatile("s_waitcnt vmcnt(2)" ::: "memory");  // own chunk-c (and A) landed
            } else {
                asm volatile("s_waitcnt vmcnt(0)" ::: "memory");
            }
            __builtin_amdgcn_s_barrier();            // all waves' chunk-c loads landed
            __builtin_amdgcn_sched_barrier(0);

            // A fragments (K slice ks*32 of tile: groups ks*4+kg, swizzle ^col)
            half8 a[4];
            #pragma unroll
            for (int mi = 0; mi < 4; ++mi) {
                int row = wm * 64 + mi * 16 + col;             // row&15 == col
                int g = ks * 4 + kg;
                a[mi] = *(const half8*)&zbuf[(size_t)row * 256 + ((g ^ col) << 3)];
            }
            const char* bb = smem + 65536 + (ks & 1) * 8192;
            __builtin_amdgcn_s_setprio(1);
            #pragma unroll
            for (int nj = 0; nj < 4; ++nj) {
                half8 b = *(const half8*)(bb + bslot[nj]);
                #pragma unroll
                for (int mi = 0; mi < 4; ++mi)
                    acc[mi][nj] = __builtin_amdgcn_mfma_f32_16x16x32_f16(a[mi], b, acc[mi][nj], 0, 0, 0);
            }
            __builtin_amdgcn_s_setprio(0);

            if (ks == 7) {   // code-tile nt complete over K=256: score + reset
                #pragma unroll
                for (int nj = 0; nj < 4; ++nj) {
                    int nl = nt * 128 + wn * 64 + nj * 16 + col;   // < 4096, fits 16 bits
                    float cn = cnorm[split * CPS + nl];
                    #pragma unroll
                    for (int mi = 0; mi < 4; ++mi)
                        #pragma unroll
                        for (int r2 = 0; r2 < 4; ++r2) {
                            float sc = fmaf(-2.0f, acc[mi][nj][r2], cn);
                            int s = mi * 4 + r2;
                            bool bb2 = sc < val[s];
                            unsigned p = pidx[s >> 1];
                            unsigned np = (s & 1) ? ((p & 0x0000FFFFu) | ((unsigned)nl << 16))
                                                  : ((p & 0xFFFF0000u) | (unsigned)nl);
                            val[s] = bb2 ? sc : val[s];
                            pidx[s >> 1] = bb2 ? np : p;
                        }
                }
                #pragma unroll
                for (int mi = 0; mi < 4; ++mi)
                    #pragma unroll
                    for (int nj = 0; nj < 4; ++nj) acc[mi][nj] = (f32x4){0.f, 0.f, 0.f, 0.f};
            }
        }
    }

    __syncthreads();   // all waves done with A/B before cbuf aliasing

    // unpack, then top-2 butterfly across the 16 lanes sharing each token row
    float b1[16], b2[16]; int i1[16], i2[16];
    #pragma unroll
    for (int s = 0; s < 16; ++s) {
        unsigned p = pidx[s >> 1];
        int nl = (s & 1) ? (int)(p >> 16) : (int)(p & 0xFFFFu);
        b1[s] = val[s]; i1[s] = split * CPS + nl;
        b2[s] = 3.4e38f; i2[s] = 0x7ffffffe;
    }
    #pragma unroll
    for (int m = 1; m < 16; m <<= 1) {
        #pragma unroll
        for (int s = 0; s < 16; ++s) {
            float p1 = __shfl_xor(b1[s], m); int j1 = __shfl_xor(i1[s], m);
            float p2 = __shfl_xor(b2[s], m); int j2 = __shfl_xor(i2[s], m);
            ins2(p1, j1, b1[s], i1[s], b2[s], i2[s]);
            ins2(p2, j2, b1[s], i1[s], b2[s], i2[s]);
        }
    }
    // per-wave top-2 -> LDS [128 rows][2 wn], then cross-wave merge
    float4* cbuf = (float4*)smem;
    if (col == 0) {
        #pragma unroll
        for (int s = 0; s < 16; ++s) {
            int mi = s >> 2, r = s & 3;
            int row = wm * 64 + mi * 16 + kg * 4 + r;   // token row 0..127
            float4 v; v.x = b1[s]; v.y = __int_as_float(i1[s]); v.z = b2[s]; v.w = __int_as_float(i2[s]);
            cbuf[row * 2 + wn] = v;
        }
    }
    __syncthreads();
    if (tid < 128) {
        float4 a = cbuf[tid * 2 + 0];
        float4 b = cbuf[tid * 2 + 1];
        float v1 = a.x; int j1 = __float_as_int(a.y);
        float v2 = a.z; int j2 = __float_as_int(a.w);
        ins2(b.x, __float_as_int(b.y), v1, j1, v2, j2);
        ins2(b.z, __float_as_int(b.w), v1, j1, v2, j2);
        float4 o; o.x = v1; o.y = __int_as_float(j1); o.z = v2; o.w = __int_as_float(j2);
        cand[(size_t)split * NTOK + m0 + tid] = o;
    }
}

// ---------------- exact fp32 rescore of 4 candidates, gather q, loss partials ----------------
__global__ __launch_bounds__(256) void k_finalize(const _Float16* __restrict__ zh,
                                                  const _Float16* __restrict__ zl,
                                                  const float* __restrict__ cb,
                                                  const float* __restrict__ cnorm,
                                                  const float4* __restrict__ cand,
                                                  float* __restrict__ out,
                                                  float* __restrict__ partials) {
    __shared__ float blk[4];
    const int tid = threadIdx.x;
    const int w = tid >> 6, lane = tid & 63;
    const int token = blockIdx.x * 4 + w;

    int ci[4];
    #pragma unroll
    for (int s = 0; s < NSPLIT; ++s) {
        float4 c = cand[(size_t)s * NTOK + token];
        ci[2 * s]     = __float_as_int(c.y);
        ci[2 * s + 1] = __float_as_int(c.w);
    }

    half4 hv = *(const half4*)&zh[(size_t)token * DIM + lane * 4];
    half4 lv = *(const half4*)&zl[(size_t)token * DIM + lane * 4];
    float z0 = (float)hv[0] + (float)lv[0];
    float z1 = (float)hv[1] + (float)lv[1];
    float z2 = (float)hv[2] + (float)lv[2];
    float z3 = (float)hv[3] + (float)lv[3];

    const float4* cb4 = (const float4*)cb;
    float best = 3.4e38f; int bi = 0x7fffffff;
    #pragma unroll
    for (int j = 0; j < 2 * NSPLIT; ++j) {
        int idx = ci[j];
        float4 e = cb4[(size_t)idx * 64 + lane];
        float d = z0 * e.x + z1 * e.y + z2 * e.z + z3 * e.w;
        #pragma unroll
        for (int m = 32; m; m >>= 1) d += __shfl_xor(d, m);
        float sc = cnorm[idx] - 2.0f * d;
        if (sc < best || (sc == best && idx < bi)) { best = sc; bi = idx; }
    }

    float4 q = cb4[(size_t)bi * 64 + lane];
    *(float4*)&out[(size_t)token * DIM + lane * 4] = q;   // x_recon == q (STE)

    float dx = z0 - q.x, dy = z1 - q.y, dz = z2 - q.z, dw = z3 - q.w;
    float ss = dx*dx + dy*dy + dz*dz + dw*dw;
    #pragma unroll
    for (int m = 32; m; m >>= 1) ss += __shfl_xor(ss, m);
    if (lane == 0) blk[w] = ss;
    __syncthreads();
    if (tid == 0) partials[blockIdx.x] = blk[0] + blk[1] + blk[2] + blk[3];
}

// ---------------- reduce partials, write both losses ----------------
__global__ __launch_bounds__(256) void k_losses(const float* __restrict__ partials,
                                                float* __restrict__ out) {
    __shared__ float red[256];
    float s = 0.0f;
    for (int i = threadIdx.x; i < NTOK / 4; i += 256) s += partials[i];
    red[threadIdx.x] = s;
    __syncthreads();
    for (int off = 128; off; off >>= 1) {
        if ((int)threadIdx.x < off) red[threadIdx.x] += red[threadIdx.x + off];
        __syncthreads();
    }
    if (threadIdx.x == 0) {
        float l = red[0] / (float)((size_t)NTOK * DIM);
        out[(size_t)NTOK * DIM]     = l;  // dictionary_loss
        out[(size_t)NTOK * DIM + 1] = l;  // commitment_loss
    }
}

extern "C" void kernel_launch(void* const* d_in, const int* in_sizes, int n_in,
                              void* d_out, int out_size, void* d_ws, size_t ws_size,
                              hipStream_t stream) {
    const float* x  = (const float*)d_in[0];
    const float* W  = (const float*)d_in[1];
    const float* b  = (const float*)d_in[2];
    const float* cb = (const float*)d_in[3];
    float* out = (float*)d_out;

    char* ws = (char*)d_ws;
    size_t off = 0;
    _Float16* zh = (_Float16*)(ws + off); off += (size_t)NTOK * DIM * 2;     // 16 MB
    _Float16* zl = (_Float16*)(ws + off); off += (size_t)NTOK * DIM * 2;     // 16 MB
    _Float16* ch = (_Float16*)(ws + off); off += (size_t)KCB * DIM * 2;      // 4 MB
    _Float16* wh = (_Float16*)(ws + off); off += (size_t)DIM * DIM * 2;      // 128 KB
    _Float16* wl = (_Float16*)(ws + off); off += (size_t)DIM * DIM * 2;      // 128 KB
    float* cnorm = (float*)(ws + off);    off += (size_t)KCB * 4;            // 32 KB
    float4* cand = (float4*)(ws + off);   off += (size_t)NSPLIT * NTOK * 16; // 1 MB
    float* parts = (float*)(ws + off);

    // allow 80 KB dynamic LDS for k_argmin (host-side, executes at capture time)
    static hipError_t _attr_once = hipFuncSetAttribute(
        reinterpret_cast<const void*>(k_argmin),
        hipFuncAttributeMaxDynamicSharedMemorySize, 81920);
    (void)_attr_once;

    k_split<<<dim3(DIM / 4), 256, 0, stream>>>(W, wh, wl, nullptr, DIM);
    k_split<<<dim3(KCB / 4), 256, 0, stream>>>(cb, ch, nullptr, cnorm, KCB);
    k_linear<<<dim3(NTOK / 64), 256, 0, stream>>>(x, wh, wl, b, zh, zl);
    k_argmin<<<dim3(NTOK / 128 * NSPLIT), 256, 81920, stream>>>(zh, ch, cnorm, cand);
    k_finalize<<<dim3(NTOK / 4), 256, 0, stream>>>(zh, zl, cb, cnorm, cand, out, parts);
    k_losses<<<1, 256, 0, stream>>>(parts, out);
}

// Round 13
// 372.106 us; speedup vs baseline: 1.0172x; 1.0172x over previous
//
#include <hip/hip_runtime.h>

#define DIM   256
#define KCB   8192
#define NTOK  32768
#define NSPLIT 2
#define CPS   4096      // codes per split

using half8 = __attribute__((ext_vector_type(8))) _Float16;
using half4 = __attribute__((ext_vector_type(4))) _Float16;
using f32x4 = __attribute__((ext_vector_type(4))) float;

#define GLOBAL_AS(p) ((const __attribute__((address_space(1))) void*)(p))
#define LDS_AS(p)    ((__attribute__((address_space(3))) void*)(p))

__device__ __forceinline__ void ins2(float v, int i, float& b1v, int& b1i,
                                     float& b2v, int& b2i) {
    bool bet1 = (v < b1v) || (v == b1v && i < b1i);
    bool bet2 = (v < b2v) || (v == b2v && i < b2i);
    if (bet1) { b2v = b1v; b2i = b1i; b1v = v; b1i = i; }
    else if (bet2) { b2v = v; b2i = i; }
}

// ---------------- split fp32 rows into fp16 hi (+ optional lo, + optional norms) ----------------
__global__ __launch_bounds__(256) void k_split(const float* __restrict__ src,
                                               _Float16* __restrict__ hi,
                                               _Float16* __restrict__ lo,
                                               float* __restrict__ norm, int nrows) {
    int row = (int)((blockIdx.x * blockDim.x + threadIdx.x) >> 6);
    int lane = threadIdx.x & 63;
    if (row >= nrows) return;
    float4 v = *(const float4*)&src[(size_t)row * DIM + lane * 4];
    float vv[4] = {v.x, v.y, v.z, v.w};
    half4 hh, hl;
    #pragma unroll
    for (int j = 0; j < 4; ++j) {
        _Float16 h = (_Float16)vv[j];
        hh[j] = h;
        hl[j] = (_Float16)(vv[j] - (float)h);
    }
    *(half4*)&hi[(size_t)row * DIM + lane * 4] = hh;
    if (lo) *(half4*)&lo[(size_t)row * DIM + lane * 4] = hl;
    if (norm) {
        float s = v.x*v.x + v.y*v.y + v.z*v.z + v.w*v.w;
        #pragma unroll
        for (int m = 32; m; m >>= 1) s += __shfl_xor(s, m);
        if (lane == 0) norm[row] = s;
    }
}

// ---------------- z = x @ W^T + b via fp16x3 MFMA, stored as (zh, zl) ----------------
__global__ __launch_bounds__(256) void k_linear(const float* __restrict__ x,
                                                const _Float16* __restrict__ wh,
                                                const _Float16* __restrict__ wl,
                                                const float* __restrict__ bias,
                                                _Float16* __restrict__ zh,
                                                _Float16* __restrict__ zl) {
    const int tid = threadIdx.x;
    const int w = tid >> 6, lane = tid & 63;
    const int col = lane & 15, kg = lane >> 4;
    const int m0 = blockIdx.x * 64;
    const int e0 = w * 64;

    f32x4 acc[4][4];
    #pragma unroll
    for (int mi = 0; mi < 4; ++mi)
        #pragma unroll
        for (int nj = 0; nj < 4; ++nj) acc[mi][nj] = (f32x4){0.f, 0.f, 0.f, 0.f};

    for (int kc = 0; kc < 8; ++kc) {
        half8 ah[4], al[4], bh[4], bl[4];
        #pragma unroll
        for (int mi = 0; mi < 4; ++mi) {
            const float* p = &x[(size_t)(m0 + mi * 16 + col) * DIM + kc * 32 + kg * 8];
            float4 v0 = *(const float4*)p;
            float4 v1 = *(const float4*)(p + 4);
            float vv[8] = {v0.x, v0.y, v0.z, v0.w, v1.x, v1.y, v1.z, v1.w};
            #pragma unroll
            for (int j = 0; j < 8; ++j) {
                _Float16 h = (_Float16)vv[j];
                ah[mi][j] = h;
                al[mi][j] = (_Float16)(vv[j] - (float)h);
            }
        }
        #pragma unroll
        for (int nj = 0; nj < 4; ++nj) {
            size_t off = (size_t)(e0 + nj * 16 + col) * DIM + kc * 32 + kg * 8;
            bh[nj] = *(const half8*)&wh[off];
            bl[nj] = *(const half8*)&wl[off];
        }
        #pragma unroll
        for (int mi = 0; mi < 4; ++mi)
            #pragma unroll
            for (int nj = 0; nj < 4; ++nj) {
                acc[mi][nj] = __builtin_amdgcn_mfma_f32_16x16x32_f16(ah[mi], bh[nj], acc[mi][nj], 0, 0, 0);
                acc[mi][nj] = __builtin_amdgcn_mfma_f32_16x16x32_f16(ah[mi], bl[nj], acc[mi][nj], 0, 0, 0);
                acc[mi][nj] = __builtin_amdgcn_mfma_f32_16x16x32_f16(al[mi], bh[nj], acc[mi][nj], 0, 0, 0);
            }
    }
    #pragma unroll
    for (int nj = 0; nj < 4; ++nj) {
        int e = e0 + nj * 16 + col;
        float bv = bias[e];
        #pragma unroll
        for (int mi = 0; mi < 4; ++mi)
            #pragma unroll
            for (int r = 0; r < 4; ++r) {
                int m = m0 + mi * 16 + kg * 4 + r;
                float zv = acc[mi][nj][r] + bv;
                _Float16 h = (_Float16)zv;
                zh[(size_t)m * DIM + e] = h;
                zl[(size_t)m * DIM + e] = (_Float16)(zv - (float)h);
            }
    }
}

// ---------------- fp16 MFMA distance argmin; 256-token tiles, 512 threads, dbuf BK=32 ----------------
// R12 (128-tok, dbuf): 228 us; staged B traffic 1.07 GB at ~4.8 TB/s is the largest pipe term.
// This round doubles arithmetic intensity again: 256 tok per block -> staged B HALVES to 512 MB.
// Block: 512 thr = 8 waves (4 wm x 2 wn); tile 256 tok x 128 codes; wave stays 64x64 with
// acc[4][4] -> per-wave unified reg demand ~96 (R12 measured 92) which FITS the 128-reg cap of
// 512-thread blocks (R4/R5 spilled at demand ~190; ours is 96). LDS: A 256x512B = 128 KB +
// B 2x8 KB dbuf = 144 KB -> 1 block/CU, 8 waves = 2 waves/SIMD (same as R12).
// Step (R12-proven 2-barrier dbuf): barrier1; STAGE(c+1) [1 load/thread]; vmcnt(1) [own chunk-c
// landed, c+1 in flight]; barrier2 [all 512 loads of chunk c landed]; 16 MFMA.
// B LDS layout = R5-proven paired-row 3-bit XOR: slot8(r,kg) = (r>>1)*8 + (((r&1)*4+kg)^((r>>1)&7)).
__global__ __launch_bounds__(512) void k_argmin(const _Float16* __restrict__ zh,
                                                const _Float16* __restrict__ ch,
                                                const float* __restrict__ cnorm,
                                                float4* __restrict__ cand) {
    extern __shared__ __align__(16) char smem[];
    const int tid = threadIdx.x;
    const int w = tid >> 6, lane = tid & 63;
    const int wm = w >> 1, wn = w & 1;
    const int col = lane & 15, kg = lane >> 4;
    const int split = blockIdx.x & 1;
    const int m0 = (blockIdx.x >> 1) * 256;

    // ---- stage A once: 256 rows x 512 B = 128 KB, LDS[row][gp] = Z[row][gp ^ (row&15)]
    #pragma unroll
    for (int j = 0; j < 16; ++j) {
        int s = j * 512 + w * 64 + lane;          // 16B slot 0..8191
        int row = s >> 5;                         // token row 0..255
        int gp = s & 31;
        int g = gp ^ (row & 15);
        const _Float16* src = zh + (size_t)(m0 + row) * DIM + g * 8;
        __builtin_amdgcn_global_load_lds(GLOBAL_AS(src),
            LDS_AS(smem + j * 8192 + w * 1024), 16, 0, 0);
    }

    // ---- B staging: 1 slot/thread of the 512-slot 8 KB chunk (R5 layout decode)
    size_t eb;
    {
        int s  = tid;                       // 16B slot 0..511
        int rr = s >> 3, q = s & 7;
        int g2 = q ^ (rr & 7);
        int r  = rr * 2 + (g2 >> 2);        // code row 0..127
        int kc4 = g2 & 3;                   // 16B group within 64B k-slice
        eb = (size_t)(split * CPS + r) * DIM + kc4 * 8;
    }
    // ---- per-thread B-read byte offsets (loop-invariant)
    int bslot[4];
    #pragma unroll
    for (int nj = 0; nj < 4; ++nj) {
        int r = wn * 64 + nj * 16 + col;    // code row 0..127 in chunk
        bslot[nj] = (((r >> 1) << 3) + ((((r & 1) << 2) + kg) ^ ((r >> 1) & 7))) << 4;
    }

    auto STAGE = [&](int cc, int buf) {
        size_t off = (size_t)(cc >> 3) * 128 * DIM + (cc & 7) * 32;   // uniform across lanes
        __builtin_amdgcn_global_load_lds(GLOBAL_AS(ch + eb + off),
            LDS_AS(smem + 131072 + buf * 8192 + w * 1024), 16, 0, 0);
    };

    STAGE(0, 0);   // chunk 0; A (16) + 1 = 17 outstanding per thread

    float val[16];
    unsigned pidx[8];
    #pragma unroll
    for (int s = 0; s < 16; ++s) val[s] = 3.4e38f;
    #pragma unroll
    for (int s = 0; s < 8; ++s) pidx[s] = 0xFFFFFFFFu;

    f32x4 acc[4][4];
    #pragma unroll
    for (int mi = 0; mi < 4; ++mi)
        #pragma unroll
        for (int nj = 0; nj < 4; ++nj) acc[mi][nj] = (f32x4){0.f, 0.f, 0.f, 0.f};

    const _Float16* zbuf = (const _Float16*)smem;

    for (int nt = 0; nt < 32; ++nt) {
        #pragma unroll
        for (int ks = 0; ks < 8; ++ks) {
            const int c = nt * 8 + ks;
            __builtin_amdgcn_s_barrier();            // readers of buf[(c+1)&1] (chunk c-1) done
            if (c < 255) {
                STAGE(c + 1, (ks + 1) & 1);
                asm volatile("s_waitcnt vmcnt(1)" ::: "memory");  // own chunk-c (and A) landed
            } else {
                asm volatile("s_waitcnt vmcnt(0)" ::: "memory");
            }
            __builtin_amdgcn_s_barrier();            // all 512 loads of chunk c landed
            __builtin_amdgcn_sched_barrier(0);

            // A fragments (K slice ks*32: groups ks*4+kg, swizzle ^col since row&15==col)
            half8 a[4];
            #pragma unroll
            for (int mi = 0; mi < 4; ++mi) {
                int row = wm * 64 + mi * 16 + col;
                int g = ks * 4 + kg;
                a[mi] = *(const half8*)&zbuf[(size_t)row * 256 + ((g ^ col) << 3)];
            }
            const char* bb = smem + 131072 + (ks & 1) * 8192;
            __builtin_amdgcn_s_setprio(1);
            #pragma unroll
            for (int nj = 0; nj < 4; ++nj) {
                half8 b = *(const half8*)(bb + bslot[nj]);
                #pragma unroll
                for (int mi = 0; mi < 4; ++mi)
                    acc[mi][nj] = __builtin_amdgcn_mfma_f32_16x16x32_f16(a[mi], b, acc[mi][nj], 0, 0, 0);
            }
            __builtin_amdgcn_s_setprio(0);

            if (ks == 7) {   // code-tile nt complete over K=256: score + reset
                #pragma unroll
                for (int nj = 0; nj < 4; ++nj) {
                    int nl = nt * 128 + wn * 64 + nj * 16 + col;   // < 4096, fits 16 bits
                    float cn = cnorm[split * CPS + nl];
                    #pragma unroll
                    for (int mi = 0; mi < 4; ++mi)
                        #pragma unroll
                        for (int r2 = 0; r2 < 4; ++r2) {
                            float sc = fmaf(-2.0f, acc[mi][nj][r2], cn);
                            int s = mi * 4 + r2;
                            bool bb2 = sc < val[s];
                            unsigned p = pidx[s >> 1];
                            unsigned np = (s & 1) ? ((p & 0x0000FFFFu) | ((unsigned)nl << 16))
                                                  : ((p & 0xFFFF0000u) | (unsigned)nl);
                            val[s] = bb2 ? sc : val[s];
                            pidx[s >> 1] = bb2 ? np : p;
                        }
                }
                #pragma unroll
                for (int mi = 0; mi < 4; ++mi)
                    #pragma unroll
                    for (int nj = 0; nj < 4; ++nj) acc[mi][nj] = (f32x4){0.f, 0.f, 0.f, 0.f};
            }
        }
    }

    __syncthreads();   // all waves done with A/B before cbuf aliasing

    // unpack, then top-2 butterfly across the 16 lanes sharing each token row
    float b1[16], b2[16]; int i1[16], i2[16];
    #pragma unroll
    for (int s = 0; s < 16; ++s) {
        unsigned p = pidx[s >> 1];
        int nl = (s & 1) ? (int)(p >> 16) : (int)(p & 0xFFFFu);
        b1[s] = val[s]; i1[s] = split * CPS + nl;
        b2[s] = 3.4e38f; i2[s] = 0x7ffffffe;
    }
    #pragma unroll
    for (int m = 1; m < 16; m <<= 1) {
        #pragma unroll
        for (int s = 0; s < 16; ++s) {
            float p1 = __shfl_xor(b1[s], m); int j1 = __shfl_xor(i1[s], m);
            float p2 = __shfl_xor(b2[s], m); int j2 = __shfl_xor(i2[s], m);
            ins2(p1, j1, b1[s], i1[s], b2[s], i2[s]);
            ins2(p2, j2, b1[s], i1[s], b2[s], i2[s]);
        }
    }
    // per-wave top-2 -> LDS [256 rows][2 wn], then cross-wave merge
    float4* cbuf = (float4*)smem;   // aliases A region (dead)
    if (col == 0) {
        #pragma unroll
        for (int s = 0; s < 16; ++s) {
            int mi = s >> 2, r = s & 3;
            int row = wm * 64 + mi * 16 + kg * 4 + r;   // token row 0..255
            float4 v; v.x = b1[s]; v.y = __int_as_float(i1[s]); v.z = b2[s]; v.w = __int_as_float(i2[s]);
            cbuf[row * 2 + wn] = v;
        }
    }
    __syncthreads();
    if (tid < 256) {
        float4 a = cbuf[tid * 2 + 0];
        float4 b = cbuf[tid * 2 + 1];
        float v1 = a.x; int j1 = __float_as_int(a.y);
        float v2 = a.z; int j2 = __float_as_int(a.w);
        ins2(b.x, __float_as_int(b.y), v1, j1, v2, j2);
        ins2(b.z, __float_as_int(b.w), v1, j1, v2, j2);
        float4 o; o.x = v1; o.y = __int_as_float(j1); o.z = v2; o.w = __int_as_float(j2);
        cand[(size_t)split * NTOK + m0 + tid] = o;
    }
}

// ---------------- exact fp32 rescore of 4 candidates, gather q, loss partials ----------------
__global__ __launch_bounds__(256) void k_finalize(const _Float16* __restrict__ zh,
                                                  const _Float16* __restrict__ zl,
                                                  const float* __restrict__ cb,
                                                  const float* __restrict__ cnorm,
                                                  const float4* __restrict__ cand,
                                                  float* __restrict__ out,
                                                  float* __restrict__ partials) {
    __shared__ float blk[4];
    const int tid = threadIdx.x;
    const int w = tid >> 6, lane = tid & 63;
    const int token = blockIdx.x * 4 + w;

    int ci[4];
    #pragma unroll
    for (int s = 0; s < NSPLIT; ++s) {
        float4 c = cand[(size_t)s * NTOK + token];
        ci[2 * s]     = __float_as_int(c.y);
        ci[2 * s + 1] = __float_as_int(c.w);
    }

    half4 hv = *(const half4*)&zh[(size_t)token * DIM + lane * 4];
    half4 lv = *(const half4*)&zl[(size_t)token * DIM + lane * 4];
    float z0 = (float)hv[0] + (float)lv[0];
    float z1 = (float)hv[1] + (float)lv[1];
    float z2 = (float)hv[2] + (float)lv[2];
    float z3 = (float)hv[3] + (float)lv[3];

    const float4* cb4 = (const float4*)cb;
    float best = 3.4e38f; int bi = 0x7fffffff;
    #pragma unroll
    for (int j = 0; j < 2 * NSPLIT; ++j) {
        int idx = ci[j];
        float4 e = cb4[(size_t)idx * 64 + lane];
        float d = z0 * e.x + z1 * e.y + z2 * e.z + z3 * e.w;
        #pragma unroll
        for (int m = 32; m; m >>= 1) d += __shfl_xor(d, m);
        float sc = cnorm[idx] - 2.0f * d;
        if (sc < best || (sc == best && idx < bi)) { best = sc; bi = idx; }
    }

    float4 q = cb4[(size_t)bi * 64 + lane];
    *(float4*)&out[(size_t)token * DIM + lane * 4] = q;   // x_recon == q (STE)

    float dx = z0 - q.x, dy = z1 - q.y, dz = z2 - q.z, dw = z3 - q.w;
    float ss = dx*dx + dy*dy + dz*dz + dw*dw;
    #pragma unroll
    for (int m = 32; m; m >>= 1) ss += __shfl_xor(ss, m);
    if (lane == 0) blk[w] = ss;
    __syncthreads();
    if (tid == 0) partials[blockIdx.x] = blk[0] + blk[1] + blk[2] + blk[3];
}

// ---------------- reduce partials, write both losses ----------------
__global__ __launch_bounds__(256) void k_losses(const float* __restrict__ partials,
                                                float* __restrict__ out) {
    __shared__ float red[256];
    float s = 0.0f;
    for (int i = threadIdx.x; i < NTOK / 4; i += 256) s += partials[i];
    red[threadIdx.x] = s;
    __syncthreads();
    for (int off = 128; off; off >>= 1) {
        if ((int)threadIdx.x < off) red[threadIdx.x] += red[threadIdx.x + off];
        __syncthreads();
    }
    if (threadIdx.x == 0) {
        float l = red[0] / (float)((size_t)NTOK * DIM);
        out[(size_t)NTOK * DIM]     = l;  // dictionary_loss
        out[(size_t)NTOK * DIM + 1] = l;  // commitment_loss
    }
}

extern "C" void kernel_launch(void* const* d_in, const int* in_sizes, int n_in,
                              void* d_out, int out_size, void* d_ws, size_t ws_size,
                              hipStream_t stream) {
    const float* x  = (const float*)d_in[0];
    const float* W  = (const float*)d_in[1];
    const float* b  = (const float*)d_in[2];
    const float* cb = (const float*)d_in[3];
    float* out = (float*)d_out;

    char* ws = (char*)d_ws;
    size_t off = 0;
    _Float16* zh = (_Float16*)(ws + off); off += (size_t)NTOK * DIM * 2;     // 16 MB
    _Float16* zl = (_Float16*)(ws + off); off += (size_t)NTOK * DIM * 2;     // 16 MB
    _Float16* ch = (_Float16*)(ws + off); off += (size_t)KCB * DIM * 2;      // 4 MB
    _Float16* wh = (_Float16*)(ws + off); off += (size_t)DIM * DIM * 2;      // 128 KB
    _Float16* wl = (_Float16*)(ws + off); off += (size_t)DIM * DIM * 2;      // 128 KB
    float* cnorm = (float*)(ws + off);    off += (size_t)KCB * 4;            // 32 KB
    float4* cand = (float4*)(ws + off);   off += (size_t)NSPLIT * NTOK * 16; // 1 MB
    float* parts = (float*)(ws + off);

    // allow 144 KB dynamic LDS for k_argmin (host-side, executes at capture time)
    static hipError_t _attr_once = hipFuncSetAttribute(
        reinterpret_cast<const void*>(k_argmin),
        hipFuncAttributeMaxDynamicSharedMemorySize, 147456);
    (void)_attr_once;

    k_split<<<dim3(DIM / 4), 256, 0, stream>>>(W, wh, wl, nullptr, DIM);
    k_split<<<dim3(KCB / 4), 256, 0, stream>>>(cb, ch, nullptr, cnorm, KCB);
    k_linear<<<dim3(NTOK / 64), 256, 0, stream>>>(x, wh, wl, b, zh, zl);
    k_argmin<<<dim3(NTOK / 256 * NSPLIT), 512, 147456, stream>>>(zh, ch, cnorm, cand);
    k_finalize<<<dim3(NTOK / 4), 256, 0, stream>>>(zh, zl, cb, cnorm, cand, out, parts);
    k_losses<<<1, 256, 0, stream>>>(parts, out);
}

// Round 14
// 370.626 us; speedup vs baseline: 1.0213x; 1.0040x over previous
//
#include <hip/hip_runtime.h>

#define DIM   256
#define KCB   8192
#define NTOK  32768
#define NSPLIT 2
#define CPS   4096      // codes per split

using half8 = __attribute__((ext_vector_type(8))) _Float16;
using half4 = __attribute__((ext_vector_type(4))) _Float16;
using f32x4 = __attribute__((ext_vector_type(4))) float;

#define GLOBAL_AS(p) ((const __attribute__((address_space(1))) void*)(p))
#define LDS_AS(p)    ((__attribute__((address_space(3))) void*)(p))

__device__ __forceinline__ void ins2(float v, int i, float& b1v, int& b1i,
                                     float& b2v, int& b2i) {
    bool bet1 = (v < b1v) || (v == b1v && i < b1i);
    bool bet2 = (v < b2v) || (v == b2v && i < b2i);
    if (bet1) { b2v = b1v; b2i = b1i; b1v = v; b1i = i; }
    else if (bet2) { b2v = v; b2i = i; }
}

// ---------------- split fp32 rows into fp16 hi (+ optional lo, + optional norms) ----------------
__global__ __launch_bounds__(256) void k_split(const float* __restrict__ src,
                                               _Float16* __restrict__ hi,
                                               _Float16* __restrict__ lo,
                                               float* __restrict__ norm, int nrows) {
    int row = (int)((blockIdx.x * blockDim.x + threadIdx.x) >> 6);
    int lane = threadIdx.x & 63;
    if (row >= nrows) return;
    float4 v = *(const float4*)&src[(size_t)row * DIM + lane * 4];
    float vv[4] = {v.x, v.y, v.z, v.w};
    half4 hh, hl;
    #pragma unroll
    for (int j = 0; j < 4; ++j) {
        _Float16 h = (_Float16)vv[j];
        hh[j] = h;
        hl[j] = (_Float16)(vv[j] - (float)h);
    }
    *(half4*)&hi[(size_t)row * DIM + lane * 4] = hh;
    if (lo) *(half4*)&lo[(size_t)row * DIM + lane * 4] = hl;
    if (norm) {
        float s = v.x*v.x + v.y*v.y + v.z*v.z + v.w*v.w;
        #pragma unroll
        for (int m = 32; m; m >>= 1) s += __shfl_xor(s, m);
        if (lane == 0) norm[row] = s;
    }
}

// ---------------- z = x @ W^T + b via fp16x3 MFMA, stored as (zh, zl) ----------------
// Epilogue rewritten (R14): old version issued 128 scalar 2B global stores/thread
// (4-row x 32B segments -- poor write coalescing on 32 MB). Now: LDS-transpose the
// 64x256 z-tile (32 KB, XOR-swizzled: byte ^= (ml&15)<<4, ~2-way write conflicts,
// conflict-free b128 row reads), then 8 fully-coalesced half8 stores/thread/pass.
__global__ __launch_bounds__(256) void k_linear(const float* __restrict__ x,
                                                const _Float16* __restrict__ wh,
                                                const _Float16* __restrict__ wl,
                                                const float* __restrict__ bias,
                                                _Float16* __restrict__ zh,
                                                _Float16* __restrict__ zl) {
    __shared__ __align__(16) _Float16 zt[64 * 256];   // 32 KB transpose buffer
    const int tid = threadIdx.x;
    const int w = tid >> 6, lane = tid & 63;
    const int col = lane & 15, kg = lane >> 4;
    const int m0 = blockIdx.x * 64;
    const int e0 = w * 64;

    f32x4 acc[4][4];
    #pragma unroll
    for (int mi = 0; mi < 4; ++mi)
        #pragma unroll
        for (int nj = 0; nj < 4; ++nj) acc[mi][nj] = (f32x4){0.f, 0.f, 0.f, 0.f};

    for (int kc = 0; kc < 8; ++kc) {
        half8 ah[4], al[4], bh[4], bl[4];
        #pragma unroll
        for (int mi = 0; mi < 4; ++mi) {
            const float* p = &x[(size_t)(m0 + mi * 16 + col) * DIM + kc * 32 + kg * 8];
            float4 v0 = *(const float4*)p;
            float4 v1 = *(const float4*)(p + 4);
            float vv[8] = {v0.x, v0.y, v0.z, v0.w, v1.x, v1.y, v1.z, v1.w};
            #pragma unroll
            for (int j = 0; j < 8; ++j) {
                _Float16 h = (_Float16)vv[j];
                ah[mi][j] = h;
                al[mi][j] = (_Float16)(vv[j] - (float)h);
            }
        }
        #pragma unroll
        for (int nj = 0; nj < 4; ++nj) {
            size_t off = (size_t)(e0 + nj * 16 + col) * DIM + kc * 32 + kg * 8;
            bh[nj] = *(const half8*)&wh[off];
            bl[nj] = *(const half8*)&wl[off];
        }
        #pragma unroll
        for (int mi = 0; mi < 4; ++mi)
            #pragma unroll
            for (int nj = 0; nj < 4; ++nj) {
                acc[mi][nj] = __builtin_amdgcn_mfma_f32_16x16x32_f16(ah[mi], bh[nj], acc[mi][nj], 0, 0, 0);
                acc[mi][nj] = __builtin_amdgcn_mfma_f32_16x16x32_f16(ah[mi], bl[nj], acc[mi][nj], 0, 0, 0);
                acc[mi][nj] = __builtin_amdgcn_mfma_f32_16x16x32_f16(al[mi], bh[nj], acc[mi][nj], 0, 0, 0);
            }
    }

    // bias in place
    #pragma unroll
    for (int nj = 0; nj < 4; ++nj) {
        float bv = bias[e0 + nj * 16 + col];
        #pragma unroll
        for (int mi = 0; mi < 4; ++mi)
            #pragma unroll
            for (int r = 0; r < 4; ++r) acc[mi][nj][r] += bv;
    }

    // pass 1: hi halves via LDS transpose
    #pragma unroll
    for (int mi = 0; mi < 4; ++mi)
        #pragma unroll
        for (int nj = 0; nj < 4; ++nj)
            #pragma unroll
            for (int r = 0; r < 4; ++r) {
                int ml = mi * 16 + kg * 4 + r;
                int e  = e0 + nj * 16 + col;
                int byte = ml * 512 + ((e * 2) ^ ((ml & 15) << 4));
                *(_Float16*)((char*)zt + byte) = (_Float16)acc[mi][nj][r];
            }
    __syncthreads();
    #pragma unroll
    for (int j = 0; j < 8; ++j) {
        int slot = j * 256 + tid;
        int row = slot >> 5, g16 = slot & 31;
        half8 v = *(const half8*)((const char*)zt + row * 512 + ((g16 ^ (row & 15)) << 4));
        *(half8*)&zh[(size_t)(m0 + row) * DIM + g16 * 8] = v;
    }
    __syncthreads();
    // pass 2: lo halves
    #pragma unroll
    for (int mi = 0; mi < 4; ++mi)
        #pragma unroll
        for (int nj = 0; nj < 4; ++nj)
            #pragma unroll
            for (int r = 0; r < 4; ++r) {
                int ml = mi * 16 + kg * 4 + r;
                int e  = e0 + nj * 16 + col;
                int byte = ml * 512 + ((e * 2) ^ ((ml & 15) << 4));
                float zv = acc[mi][nj][r];
                _Float16 h = (_Float16)zv;
                *(_Float16*)((char*)zt + byte) = (_Float16)(zv - (float)h);
            }
    __syncthreads();
    #pragma unroll
    for (int j = 0; j < 8; ++j) {
        int slot = j * 256 + tid;
        int row = slot >> 5, g16 = slot & 31;
        half8 v = *(const half8*)((const char*)zt + row * 512 + ((g16 ^ (row & 15)) << 4));
        *(half8*)&zl[(size_t)(m0 + row) * DIM + g16 * 8] = v;
    }
}

// ---------------- fp16 MFMA distance argmin; 128-tok tiles + double-buffered BK=32 (R12-proven) ----------------
// Session best for this kernel: 228 us (R12). 128 tok x 128 codes per block, 4 waves (2wm x 2wn),
// acc[4][4]=64 AGPR, VGPR=92, no spill. LDS: A 64 KB (swizzle ^col) + B 2x8 KB dbuf = 80 KB
// -> 2 blocks/CU with INDEPENDENT barriers. Step: barrier1; STAGE(c+1); vmcnt(2); barrier2; 16 MFMA.
// B LDS layout = R5-proven paired-row 3-bit XOR: slot8(r,kg) = (r>>1)*8 + (((r&1)*4+kg)^((r>>1)&7)).
__global__ __launch_bounds__(256, 1) void k_argmin(const _Float16* __restrict__ zh,
                                                   const _Float16* __restrict__ ch,
                                                   const float* __restrict__ cnorm,
                                                   float4* __restrict__ cand) {
    extern __shared__ __align__(16) char smem[];
    const int tid = threadIdx.x;
    const int w = tid >> 6, lane = tid & 63;
    const int wm = w >> 1, wn = w & 1;
    const int col = lane & 15, kg = lane >> 4;
    const int split = blockIdx.x & 1;
    const int m0 = (blockIdx.x >> 1) * 128;

    // ---- stage A once: 128 rows x 512 B, LDS[row][gp] = Z[row][gp ^ (row&15)]  (16 loads/thread)
    #pragma unroll
    for (int j = 0; j < 16; ++j) {
        int s = j * 256 + w * 64 + lane;          // 16B slot 0..4095
        int row = s >> 5;                         // token row 0..127
        int gp = s & 31;
        int g = gp ^ (row & 15);
        const _Float16* src = zh + (size_t)(m0 + row) * DIM + g * 8;
        __builtin_amdgcn_global_load_lds(GLOBAL_AS(src),
            LDS_AS(smem + j * 4096 + w * 1024), 16, 0, 0);
    }

    // ---- B staging: per-thread global element offsets (loop-invariant part).
    size_t eb[2];
    #pragma unroll
    for (int j = 0; j < 2; ++j) {
        int s  = j * 256 + w * 64 + lane;   // 16B slot 0..511
        int rr = s >> 3, q = s & 7;
        int g2 = q ^ (rr & 7);
        int r  = rr * 2 + (g2 >> 2);        // code row 0..127
        int kg4 = g2 & 3;                   // 16B group within 64B k-slice
        eb[j] = (size_t)(split * CPS + r) * DIM + kg4 * 8;
    }
    // ---- per-thread B-read byte offsets (loop-invariant)
    int bslot[4];
    #pragma unroll
    for (int nj = 0; nj < 4; ++nj) {
        int r = wn * 64 + nj * 16 + col;    // code row 0..127 in chunk
        bslot[nj] = (((r >> 1) << 3) + ((((r & 1) << 2) + kg) ^ ((r >> 1) & 7))) << 4;
    }

    auto STAGE = [&](int cc, int buf) {
        size_t off = (size_t)(cc >> 3) * 128 * DIM + (cc & 7) * 32;   // uniform across lanes
        char* dst = smem + 65536 + buf * 8192 + w * 1024;
        #pragma unroll
        for (int j = 0; j < 2; ++j)
            __builtin_amdgcn_global_load_lds(GLOBAL_AS(ch + eb[j] + off),
                                             LDS_AS(dst + j * 4096), 16, 0, 0);
    };

    STAGE(0, 0);   // chunk 0

    float val[16];
    unsigned pidx[8];
    #pragma unroll
    for (int s = 0; s < 16; ++s) val[s] = 3.4e38f;
    #pragma unroll
    for (int s = 0; s < 8; ++s) pidx[s] = 0xFFFFFFFFu;

    f32x4 acc[4][4];
    #pragma unroll
    for (int mi = 0; mi < 4; ++mi)
        #pragma unroll
        for (int nj = 0; nj < 4; ++nj) acc[mi][nj] = (f32x4){0.f, 0.f, 0.f, 0.f};

    const _Float16* zbuf = (const _Float16*)smem;

    for (int nt = 0; nt < 32; ++nt) {
        #pragma unroll
        for (int ks = 0; ks < 8; ++ks) {
            const int c = nt * 8 + ks;
            __builtin_amdgcn_s_barrier();            // readers of buf[(c+1)&1] (chunk c-1) done
            if (c < 255) {
                STAGE(c + 1, (ks + 1) & 1);
                asm volatile("s_waitcnt vmcnt(2)" ::: "memory");  // own chunk-c (and A) landed
            } else {
                asm volatile("s_waitcnt vmcnt(0)" ::: "memory");
            }
            __builtin_amdgcn_s_barrier();            // all waves' chunk-c loads landed
            __builtin_amdgcn_sched_barrier(0);

            // A fragments (K slice ks*32 of tile: groups ks*4+kg, swizzle ^col)
            half8 a[4];
            #pragma unroll
            for (int mi = 0; mi < 4; ++mi) {
                int row = wm * 64 + mi * 16 + col;             // row&15 == col
                int g = ks * 4 + kg;
                a[mi] = *(const half8*)&zbuf[(size_t)row * 256 + ((g ^ col) << 3)];
            }
            const char* bb = smem + 65536 + (ks & 1) * 8192;
            __builtin_amdgcn_s_setprio(1);
            #pragma unroll
            for (int nj = 0; nj < 4; ++nj) {
                half8 b = *(const half8*)(bb + bslot[nj]);
                #pragma unroll
                for (int mi = 0; mi < 4; ++mi)
                    acc[mi][nj] = __builtin_amdgcn_mfma_f32_16x16x32_f16(a[mi], b, acc[mi][nj], 0, 0, 0);
            }
            __builtin_amdgcn_s_setprio(0);

            if (ks == 7) {   // code-tile nt complete over K=256: score + reset
                #pragma unroll
                for (int nj = 0; nj < 4; ++nj) {
                    int nl = nt * 128 + wn * 64 + nj * 16 + col;   // < 4096, fits 16 bits
                    float cn = cnorm[split * CPS + nl];
                    #pragma unroll
                    for (int mi = 0; mi < 4; ++mi)
                        #pragma unroll
                        for (int r2 = 0; r2 < 4; ++r2) {
                            float sc = fmaf(-2.0f, acc[mi][nj][r2], cn);
                            int s = mi * 4 + r2;
                            bool bb2 = sc < val[s];
                            unsigned p = pidx[s >> 1];
                            unsigned np = (s & 1) ? ((p & 0x0000FFFFu) | ((unsigned)nl << 16))
                                                  : ((p & 0xFFFF0000u) | (unsigned)nl);
                            val[s] = bb2 ? sc : val[s];
                            pidx[s >> 1] = bb2 ? np : p;
                        }
                }
                #pragma unroll
                for (int mi = 0; mi < 4; ++mi)
                    #pragma unroll
                    for (int nj = 0; nj < 4; ++nj) acc[mi][nj] = (f32x4){0.f, 0.f, 0.f, 0.f};
            }
        }
    }

    __syncthreads();   // all waves done with A/B before cbuf aliasing

    // unpack, then top-2 butterfly across the 16 lanes sharing each token row
    float b1[16], b2[16]; int i1[16], i2[16];
    #pragma unroll
    for (int s = 0; s < 16; ++s) {
        unsigned p = pidx[s >> 1];
        int nl = (s & 1) ? (int)(p >> 16) : (int)(p & 0xFFFFu);
        b1[s] = val[s]; i1[s] = split * CPS + nl;
        b2[s] = 3.4e38f; i2[s] = 0x7ffffffe;
    }
    #pragma unroll
    for (int m = 1; m < 16; m <<= 1) {
        #pragma unroll
        for (int s = 0; s < 16; ++s) {
            float p1 = __shfl_xor(b1[s], m); int j1 = __shfl_xor(i1[s], m);
            float p2 = __shfl_xor(b2[s], m); int j2 = __shfl_xor(i2[s], m);
            ins2(p1, j1, b1[s], i1[s], b2[s], i2[s]);
            ins2(p2, j2, b1[s], i1[s], b2[s], i2[s]);
        }
    }
    // per-wave top-2 -> LDS [128 rows][2 wn], then cross-wave merge
    float4* cbuf = (float4*)smem;
    if (col == 0) {
        #pragma unroll
        for (int s = 0; s < 16; ++s) {
            int mi = s >> 2, r = s & 3;
            int row = wm * 64 + mi * 16 + kg * 4 + r;   // token row 0..127
            float4 v; v.x = b1[s]; v.y = __int_as_float(i1[s]); v.z = b2[s]; v.w = __int_as_float(i2[s]);
            cbuf[row * 2 + wn] = v;
        }
    }
    __syncthreads();
    if (tid < 128) {
        float4 a = cbuf[tid * 2 + 0];
        float4 b = cbuf[tid * 2 + 1];
        float v1 = a.x; int j1 = __float_as_int(a.y);
        float v2 = a.z; int j2 = __float_as_int(a.w);
        ins2(b.x, __float_as_int(b.y), v1, j1, v2, j2);
        ins2(b.z, __float_as_int(b.w), v1, j1, v2, j2);
        float4 o; o.x = v1; o.y = __int_as_float(j1); o.z = v2; o.w = __int_as_float(j2);
        cand[(size_t)split * NTOK + m0 + tid] = o;
    }
}

// ---------------- exact fp32 rescore of 4 candidates, gather q, loss partials ----------------
__global__ __launch_bounds__(256) void k_finalize(const _Float16* __restrict__ zh,
                                                  const _Float16* __restrict__ zl,
                                                  const float* __restrict__ cb,
                                                  const float* __restrict__ cnorm,
                                                  const float4* __restrict__ cand,
                                                  float* __restrict__ out,
                                                  float* __restrict__ partials) {
    __shared__ float blk[4];
    const int tid = threadIdx.x;
    const int w = tid >> 6, lane = tid & 63;
    const int token = blockIdx.x * 4 + w;

    int ci[4];
    #pragma unroll
    for (int s = 0; s < NSPLIT; ++s) {
        float4 c = cand[(size_t)s * NTOK + token];
        ci[2 * s]     = __float_as_int(c.y);
        ci[2 * s + 1] = __float_as_int(c.w);
    }

    half4 hv = *(const half4*)&zh[(size_t)token * DIM + lane * 4];
    half4 lv = *(const half4*)&zl[(size_t)token * DIM + lane * 4];
    float z0 = (float)hv[0] + (float)lv[0];
    float z1 = (float)hv[1] + (float)lv[1];
    float z2 = (float)hv[2] + (float)lv[2];
    float z3 = (float)hv[3] + (float)lv[3];

    const float4* cb4 = (const float4*)cb;
    float best = 3.4e38f; int bi = 0x7fffffff;
    #pragma unroll
    for (int j = 0; j < 2 * NSPLIT; ++j) {
        int idx = ci[j];
        float4 e = cb4[(size_t)idx * 64 + lane];
        float d = z0 * e.x + z1 * e.y + z2 * e.z + z3 * e.w;
        #pragma unroll
        for (int m = 32; m; m >>= 1) d += __shfl_xor(d, m);
        float sc = cnorm[idx] - 2.0f * d;
        if (sc < best || (sc == best && idx < bi)) { best = sc; bi = idx; }
    }

    float4 q = cb4[(size_t)bi * 64 + lane];
    *(float4*)&out[(size_t)token * DIM + lane * 4] = q;   // x_recon == q (STE)

    float dx = z0 - q.x, dy = z1 - q.y, dz = z2 - q.z, dw = z3 - q.w;
    float ss = dx*dx + dy*dy + dz*dz + dw*dw;
    #pragma unroll
    for (int m = 32; m; m >>= 1) ss += __shfl_xor(ss, m);
    if (lane == 0) blk[w] = ss;
    __syncthreads();
    if (tid == 0) partials[blockIdx.x] = blk[0] + blk[1] + blk[2] + blk[3];
}

// ---------------- reduce partials, write both losses ----------------
__global__ __launch_bounds__(256) void k_losses(const float* __restrict__ partials,
                                                float* __restrict__ out) {
    __shared__ float red[256];
    float s = 0.0f;
    for (int i = threadIdx.x; i < NTOK / 4; i += 256) s += partials[i];
    red[threadIdx.x] = s;
    __syncthreads();
    for (int off = 128; off; off >>= 1) {
        if ((int)threadIdx.x < off) red[threadIdx.x] += red[threadIdx.x + off];
        __syncthreads();
    }
    if (threadIdx.x == 0) {
        float l = red[0] / (float)((size_t)NTOK * DIM);
        out[(size_t)NTOK * DIM]     = l;  // dictionary_loss
        out[(size_t)NTOK * DIM + 1] = l;  // commitment_loss
    }
}

extern "C" void kernel_launch(void* const* d_in, const int* in_sizes, int n_in,
                              void* d_out, int out_size, void* d_ws, size_t ws_size,
                              hipStream_t stream) {
    const float* x  = (const float*)d_in[0];
    const float* W  = (const float*)d_in[1];
    const float* b  = (const float*)d_in[2];
    const float* cb = (const float*)d_in[3];
    float* out = (float*)d_out;

    char* ws = (char*)d_ws;
    size_t off = 0;
    _Float16* zh = (_Float16*)(ws + off); off += (size_t)NTOK * DIM * 2;     // 16 MB
    _Float16* zl = (_Float16*)(ws + off); off += (size_t)NTOK * DIM * 2;     // 16 MB
    _Float16* ch = (_Float16*)(ws + off); off += (size_t)KCB * DIM * 2;      // 4 MB
    _Float16* wh = (_Float16*)(ws + off); off += (size_t)DIM * DIM * 2;      // 128 KB
    _Float16* wl = (_Float16*)(ws + off); off += (size_t)DIM * DIM * 2;      // 128 KB
    float* cnorm = (float*)(ws + off);    off += (size_t)KCB * 4;            // 32 KB
    float4* cand = (float4*)(ws + off);   off += (size_t)NSPLIT * NTOK * 16; // 1 MB
    float* parts = (float*)(ws + off);

    // allow 80 KB dynamic LDS for k_argmin (host-side, executes at capture time)
    static hipError_t _attr_once = hipFuncSetAttribute(
        reinterpret_cast<const void*>(k_argmin),
        hipFuncAttributeMaxDynamicSharedMemorySize, 81920);
    (void)_attr_once;

    k_split<<<dim3(DIM / 4), 256, 0, stream>>>(W, wh, wl, nullptr, DIM);
    k_split<<<dim3(KCB / 4), 256, 0, stream>>>(cb, ch, nullptr, cnorm, KCB);
    k_linear<<<dim3(NTOK / 64), 256, 0, stream>>>(x, wh, wl, b, zh, zl);
    k_argmin<<<dim3(NTOK / 128 * NSPLIT), 256, 81920, stream>>>(zh, ch, cnorm, cand);
    k_finalize<<<dim3(NTOK / 4), 256, 0, stream>>>(zh, zl, cb, cnorm, cand, out, parts);
    k_losses<<<1, 256, 0, stream>>>(parts, out);
}